// Round 4
// baseline (129.729 us; speedup 1.0000x reference)
//
#include <hip/hip_runtime.h>
#include <hip/hip_bf16.h>
#include <math.h>

#define E_DIM 128
#define S_LEN 2048
#define B_N   8
#define BS    (B_N * S_LEN)       // 16384 positions
#define CHUNK 64
#define NCHUNK (S_LEN / CHUNK)    // 32

typedef unsigned short u16;
typedef _Float16 f16;
typedef _Float16 f16x2 __attribute__((ext_vector_type(2)));
typedef _Float16 f16x8 __attribute__((ext_vector_type(8)));
typedef float    f32x16 __attribute__((ext_vector_type(16)));

// ---------------------------------------------------------------------------
// Kernel 1 (fused): blocks 0..1023 = W pre-convert; blocks 1024..1279 = dense.
// wconv: fp32 [c][a][p] -> f16 [a][c][quad-swizzled p]; quad (a,c,qs) holds
// source quad (c,a, qs^(c&15)) so k_main's LINEAR global_load_lds staging
// lands the layout the swizzled ds_read expects (XOR involution, G21).
// dense: h = x @ W + b.
// ---------------------------------------------------------------------------
__global__ __launch_bounds__(256) void k_pre(const float* __restrict__ x,
                                             const float* __restrict__ dw,
                                             const float* __restrict__ db,
                                             const float* __restrict__ cm,
                                             float* __restrict__ hout,
                                             u16* __restrict__ wb) {
    if (blockIdx.x < 1024) {
        // ---- wconv ----
        int t = blockIdx.x * 256 + threadIdx.x;     // one 8-elem quad each
        int qs = t & 15, c = (t >> 4) & 127, a = t >> 11;
        const float* src = cm + (((long)(c << 7) + a) << 7) + ((qs ^ (c & 15)) << 3);
        float4 v0 = ((const float4*)src)[0];
        float4 v1 = ((const float4*)src)[1];
        union { f16 f[8]; uint4 v; } o;
        o.f[0] = (f16)v0.x; o.f[1] = (f16)v0.y; o.f[2] = (f16)v0.z; o.f[3] = (f16)v0.w;
        o.f[4] = (f16)v1.x; o.f[5] = (f16)v1.y; o.f[6] = (f16)v1.z; o.f[7] = (f16)v1.w;
        ((uint4*)wb)[t] = o.v;
        return;
    }
    // ---- dense ----
    __shared__ float Wl[E_DIM * E_DIM];   // [k][c], 64KB
    const int t = threadIdx.x;
    const long r0 = (long)(blockIdx.x - 1024) * 64;

    float4* Wl4 = (float4*)Wl;
    const float4* w4 = (const float4*)dw;
#pragma unroll
    for (int i = 0; i < 16; ++i) Wl4[t + 256 * i] = w4[t + 256 * i];
    __syncthreads();

    const int cq = t & 31;
    const int rg = t >> 5;
    float4 bb = ((const float4*)db)[cq];
    float acc[8][4];
#pragma unroll
    for (int i = 0; i < 8; ++i) {
        acc[i][0] = bb.x; acc[i][1] = bb.y; acc[i][2] = bb.z; acc[i][3] = bb.w;
    }
#pragma unroll 4
    for (int k = 0; k < E_DIM; ++k) {
        float4 wv = Wl4[k * 32 + cq];
#pragma unroll
        for (int i = 0; i < 8; ++i) {
            float xv = x[(r0 + rg * 8 + i) * E_DIM + k];
            acc[i][0] += xv * wv.x;
            acc[i][1] += xv * wv.y;
            acc[i][2] += xv * wv.z;
            acc[i][3] += xv * wv.w;
        }
    }
    float4* h4 = (float4*)(hout + r0 * E_DIM);
#pragma unroll
    for (int i = 0; i < 8; ++i) {
        float4 o;
        o.x = acc[i][0]; o.y = acc[i][1]; o.z = acc[i][2]; o.w = acc[i][3];
        h4[(rg * 8 + i) * 32 + cq] = o;
    }
}

// ---------------------------------------------------------------------------
// Kernel 2: chunked decayed scan. Writes f16 LOCAL prefix into sb16 (carry
// applied later inside k_main), f16 transposed h into hT[a][pos], fp32
// chunk carry-out f_j into fc (raw — no rewrite).
// ---------------------------------------------------------------------------
__global__ __launch_bounds__(128) void k_scan(const float* __restrict__ h,
                                              u16* __restrict__ sb16,
                                              float* __restrict__ fc,
                                              u16* __restrict__ hT) {
    const int b = blockIdx.x >> 5;
    const int j = blockIdx.x & 31;
    const int e = threadIdx.x;
    const float inv_d = (float)(1.0 / 1.2);
    const int pos0 = b * S_LEN + j * CHUNK;
    long base = (long)pos0 * E_DIM + e;
    float carry = 0.f;
    union { u16 u[8]; uint4 v; } hb;
#pragma unroll 1
    for (int i0 = 0; i0 < CHUNK; i0 += 8) {
#pragma unroll
        for (int k = 0; k < 8; ++k) {
            float hv = h[base + (long)(i0 + k) * E_DIM];
            union { f16 f; u16 u; } cu; cu.f = (f16)carry;
            sb16[base + (long)(i0 + k) * E_DIM] = cu.u;
            union { f16 f; u16 u; } hu; hu.f = (f16)hv;
            hb.u[k] = hu.u;
            carry = (carry + hv) * inv_d;
        }
        *(uint4*)&hT[(size_t)e * BS + pos0 + i0] = hb.v;
    }
    fc[(b * NCHUNK + j) * E_DIM + e] = carry;
}

// ---------------------------------------------------------------------------
// Kernel 3 (main): f16 MFMA einsum, carry-combine + decay-fix fused into the
// prologue.  Grid 512 = (mb 0..127) x (r 0..3), bid = mb*4+r so each XCD
// serves a single W K-half (L2-resident).  Block: 256 thr = 4 waves, owns
// 128 rows x 128 c x 32 a-slices; 2 independent blocks/CU fill each other's
// barrier stalls.  Wave (rbp=w>>1, ntp=w&1) owns 64 rows x 64 c.
// s packed f16x2 in 64 VGPRs; A-frags via v_pk_mul_f16; W a-slice (32KB)
// double-buffered via global_load_lds width=16.
// ---------------------------------------------------------------------------
__global__ __launch_bounds__(256, 2) void k_main(const u16* __restrict__ hT,
                                                 const u16* __restrict__ sb16,
                                                 const float* __restrict__ fc,
                                                 const u16* __restrict__ wb,
                                                 float* __restrict__ out,
                                                 float dm64) {
    __shared__ u16 Wl[2][16384];     // 2 x 32KB
    __shared__ float carr[2][E_DIM]; // carry-in for the block's two chunks
    const int t = threadIdx.x;
    const int w = t >> 6, l = t & 63;
    const int l31 = l & 31, hi = l >> 5;
    const int mb = blockIdx.x >> 2, r = blockIdx.x & 3;
    const int rbp = w >> 1, ntp = w & 1;

    const u16* wbK = wb + (size_t)(r * 32) * 16384;

#define STAGE(buf, sl) {                                                          \
    const u16* gsrc = wbK + (size_t)(sl) * 16384 + t * 8;                         \
    _Pragma("unroll")                                                             \
    for (int i = 0; i < 8; ++i)                                                   \
        __builtin_amdgcn_global_load_lds(                                         \
            (const __attribute__((address_space(1))) void*)(gsrc + i * 2048),     \
            (__attribute__((address_space(3))) void*)&Wl[buf][t * 8 + i * 2048],  \
            16, 0, 0); }

    STAGE(0, 0);

    // ---- fused k_carry: serial chunk-carry recurrence for this block's 2 chunks
    const int row_base = mb * 128;
    const int bb = row_base >> 11;            // batch
    const int j0 = (row_base >> 6) & 31;      // first chunk
    {
        const int ch = t >> 7;                // 0,1
        const int e  = t & 127;
        const int jend = j0 + ch;
        float c = 0.f;
        for (int jj = 0; jj < jend; ++jj)
            c = fc[(bb * NCHUNK + jj) * E_DIM + e] + c * dm64;
        carr[ch][e] = c;
    }
    __syncthreads();   // carr ready; also drains STAGE(0)

    // ---- fused k_fix: s2 fragments = f16(local_prefix + carry * 1.2^-i)
    const float L2D = 0.26303440583379383f;   // log2(1.2)
    f16x2 s2[2][32];
#pragma unroll
    for (int rb = 0; rb < 2; ++rb) {
        const int row = row_base + rbp * 64 + rb * 32 + l31;
        const float f = exp2f(-L2D * (float)(row & 63));
        const uint4* sp = (const uint4*)(sb16 + (size_t)row * E_DIM + hi * 8);
#pragma unroll
        for (int ks = 0; ks < 8; ++ks) {
            union { uint4 u; u16 us[8]; } uu; uu.u = sp[ks * 2];
            const float* cp = &carr[rbp][ks * 16 + hi * 8];
#pragma unroll
            for (int q = 0; q < 4; ++q) {
                union { f16 f; u16 u; } a0; a0.u = uu.us[2 * q];
                union { f16 f; u16 u; } a1; a1.u = uu.us[2 * q + 1];
                f16x2 pr;
                pr.x = (f16)((float)a0.f + cp[2 * q] * f);
                pr.y = (f16)((float)a1.f + cp[2 * q + 1] * f);
                s2[rb][ks * 4 + q] = pr;
            }
        }
    }

    f32x16 acc[2][2];
#pragma unroll
    for (int rb = 0; rb < 2; ++rb)
#pragma unroll
        for (int nt = 0; nt < 2; ++nt)
#pragma unroll
            for (int g = 0; g < 16; ++g) acc[rb][nt][g] = 0.f;

    const u16* hTb = hT + (size_t)mb * 128 + rbp * 64 + l31;
    u16 h0 = hTb[(size_t)(r * 32) * BS];
    u16 h1 = hTb[(size_t)(r * 32) * BS + 32];

    const int sxb = l31 & 15;
    const int wcoff = (ntp * 64 + l31) * E_DIM;

#pragma unroll 1
    for (int sl = 0; sl < 32; ++sl) {
        const int cur = sl & 1;
        if (sl < 31) {
            if (cur) STAGE(0, sl + 1) else STAGE(1, sl + 1);
        }
        u16 nh0 = 0, nh1 = 0;
        if (sl < 31) {
            nh0 = hTb[(size_t)(r * 32 + sl + 1) * BS];
            nh1 = hTb[(size_t)(r * 32 + sl + 1) * BS + 32];
        }

        union { u16 u[2]; f16x2 v; } hu0, hu1;
        hu0.u[0] = h0; hu0.u[1] = h0;
        hu1.u[0] = h1; hu1.u[1] = h1;
        const u16* Wc = &Wl[cur][wcoff];
#pragma unroll
        for (int ks = 0; ks < 8; ++ks) {
            const int sx = ((ks << 1) + hi) ^ sxb;
            f16x8 b0 = *(const f16x8*)(Wc + sx * 8);
            f16x8 b1 = *(const f16x8*)(Wc + 32 * E_DIM + sx * 8);
            union { f16x2 h2[4]; f16x8 v; } a0, a1;
#pragma unroll
            for (int q = 0; q < 4; ++q) {
                a0.h2[q] = hu0.v * s2[0][ks * 4 + q];
                a1.h2[q] = hu1.v * s2[1][ks * 4 + q];
            }
            acc[0][0] = __builtin_amdgcn_mfma_f32_32x32x16_f16(a0.v, b0, acc[0][0], 0, 0, 0);
            acc[0][1] = __builtin_amdgcn_mfma_f32_32x32x16_f16(a0.v, b1, acc[0][1], 0, 0, 0);
            acc[1][0] = __builtin_amdgcn_mfma_f32_32x32x16_f16(a1.v, b0, acc[1][0], 0, 0, 0);
            acc[1][1] = __builtin_amdgcn_mfma_f32_32x32x16_f16(a1.v, b1, acc[1][1], 0, 0, 0);
        }
        h0 = nh0; h1 = nh1;
        __syncthreads();
    }
#undef STAGE

    // epilogue: K-split partials via hw fp32 atomics (out pre-zeroed)
#pragma unroll
    for (int rb = 0; rb < 2; ++rb)
#pragma unroll
        for (int nt = 0; nt < 2; ++nt)
#pragma unroll
            for (int g = 0; g < 16; ++g) {
                int rowl = (g & 3) + 8 * (g >> 2) + 4 * hi;   // m101 C/D map
                long row = (long)row_base + rbp * 64 + rb * 32 + rowl;
                int col = ntp * 64 + nt * 32 + l31;
                unsafeAtomicAdd(&out[row * E_DIM + col], acc[rb][nt][g]);
            }
}

// ---------------------------------------------------------------------------
// Kernel 4: residual + LayerNorm, in place on d_out. 8 rows/block.
// ---------------------------------------------------------------------------
__global__ __launch_bounds__(256) void k_ln(float* __restrict__ out,
                                            const float* __restrict__ h,
                                            const float* __restrict__ gamma,
                                            const float* __restrict__ beta) {
    const int t = threadIdx.x;
    const int l32 = t & 31, rl = t >> 5;
    const long row = (long)blockIdx.x * 8 + rl;
    float4 v  = ((const float4*)out)[row * 32 + l32];
    float4 hv = ((const float4*)h)[row * 32 + l32];
    v.x += hv.x; v.y += hv.y; v.z += hv.z; v.w += hv.w;
    float ls = v.x + v.y + v.z + v.w;
    float lq = v.x * v.x + v.y * v.y + v.z * v.z + v.w * v.w;
#pragma unroll
    for (int m = 1; m < 32; m <<= 1) {
        ls += __shfl_xor(ls, m, 64);
        lq += __shfl_xor(lq, m, 64);
    }
    float mean = ls * (1.f / 128.f);
    float var  = lq * (1.f / 128.f) - mean * mean;
    float inv  = rsqrtf(var + 1e-3f);
    float4 g = ((const float4*)gamma)[l32];
    float4 b = ((const float4*)beta)[l32];
    float4 o;
    o.x = (v.x - mean) * inv * g.x + b.x;
    o.y = (v.y - mean) * inv * g.y + b.y;
    o.z = (v.z - mean) * inv * g.z + b.z;
    o.w = (v.w - mean) * inv * g.w + b.w;
    ((float4*)out)[row * 32 + l32] = o;
}

// ---------------------------------------------------------------------------
extern "C" void kernel_launch(void* const* d_in, const int* in_sizes, int n_in,
                              void* d_out, int out_size, void* d_ws, size_t ws_size,
                              hipStream_t stream) {
    const float* x     = (const float*)d_in[0];
    const float* dw    = (const float*)d_in[1];
    const float* db    = (const float*)d_in[2];
    const float* cm    = (const float*)d_in[3];
    const float* gamma = (const float*)d_in[4];
    const float* beta  = (const float*)d_in[5];
    float* outp = (float*)d_out;

    float* ws = (float*)d_ws;
    float* h    = ws;                                     // BS*E f32 (8 MB)
    float* fc   = ws + (size_t)BS * E_DIM;                // 32768 f32 (raw f_j)
    u16*   wb   = (u16*)(fc + B_N * NCHUNK * E_DIM);      // E^3 f16 (4 MB)
    u16*   hT   = wb + (size_t)2097152;                   // [a][pos] f16 (4 MB)
    u16*   sb16 = hT + (size_t)BS * E_DIM;                // [pos][p] f16 (4 MB)

    float dm64 = (float)pow(1.2, -64.0);   // host-side, pure CPU

    hipMemsetAsync(d_out, 0, (size_t)BS * E_DIM * sizeof(float), stream);
    k_pre <<<dim3(1280), dim3(256), 0, stream>>>(x, dw, db, cm, h, wb);
    k_scan<<<dim3(B_N * NCHUNK), dim3(128), 0, stream>>>(h, sb16, fc, hT);
    k_main<<<dim3(512), dim3(256), 0, stream>>>(hT, sb16, fc, wb, outp, dm64);
    k_ln  <<<dim3(BS / 8), dim3(256), 0, stream>>>(outp, h, gamma, beta);
}

// Round 5
// 128.972 us; speedup vs baseline: 1.0059x; 1.0059x over previous
//
#include <hip/hip_runtime.h>
#include <hip/hip_bf16.h>
#include <math.h>

#define E_DIM 128
#define S_LEN 2048
#define B_N   8
#define BS    (B_N * S_LEN)       // 16384 positions
#define CHUNK 64
#define NCHUNK (S_LEN / CHUNK)    // 32

typedef unsigned short u16;
typedef _Float16 f16;
typedef _Float16 f16x2 __attribute__((ext_vector_type(2)));
typedef _Float16 f16x8 __attribute__((ext_vector_type(8)));
typedef float    f32x16 __attribute__((ext_vector_type(16)));

// ---------------------------------------------------------------------------
// Kernel 1 (fused): blocks 0..1023 = W pre-convert; blocks 1024..1279 = dense.
// wconv: fp32 [c][a][p] -> f16 [a][c][quad-swizzled p]; quad (a,c,qs) holds
// source quad (c,a, qs^(c&15)) so k_main's LINEAR global_load_lds staging
// lands the layout the swizzled ds_read expects (XOR involution, G21).
// ---------------------------------------------------------------------------
__global__ __launch_bounds__(256) void k_pre(const float* __restrict__ x,
                                             const float* __restrict__ dw,
                                             const float* __restrict__ db,
                                             const float* __restrict__ cm,
                                             float* __restrict__ hout,
                                             u16* __restrict__ wb) {
    if (blockIdx.x < 1024) {
        int t = blockIdx.x * 256 + threadIdx.x;     // one 8-elem quad each
        int qs = t & 15, c = (t >> 4) & 127, a = t >> 11;
        const float* src = cm + (((long)(c << 7) + a) << 7) + ((qs ^ (c & 15)) << 3);
        float4 v0 = ((const float4*)src)[0];
        float4 v1 = ((const float4*)src)[1];
        union { f16 f[8]; uint4 v; } o;
        o.f[0] = (f16)v0.x; o.f[1] = (f16)v0.y; o.f[2] = (f16)v0.z; o.f[3] = (f16)v0.w;
        o.f[4] = (f16)v1.x; o.f[5] = (f16)v1.y; o.f[6] = (f16)v1.z; o.f[7] = (f16)v1.w;
        ((uint4*)wb)[t] = o.v;
        return;
    }
    __shared__ float Wl[E_DIM * E_DIM];   // [k][c], 64KB
    const int t = threadIdx.x;
    const long r0 = (long)(blockIdx.x - 1024) * 64;

    float4* Wl4 = (float4*)Wl;
    const float4* w4 = (const float4*)dw;
#pragma unroll
    for (int i = 0; i < 16; ++i) Wl4[t + 256 * i] = w4[t + 256 * i];
    __syncthreads();

    const int cq = t & 31;
    const int rg = t >> 5;
    float4 bb = ((const float4*)db)[cq];
    float acc[8][4];
#pragma unroll
    for (int i = 0; i < 8; ++i) {
        acc[i][0] = bb.x; acc[i][1] = bb.y; acc[i][2] = bb.z; acc[i][3] = bb.w;
    }
#pragma unroll 4
    for (int k = 0; k < E_DIM; ++k) {
        float4 wv = Wl4[k * 32 + cq];
#pragma unroll
        for (int i = 0; i < 8; ++i) {
            float xv = x[(r0 + rg * 8 + i) * E_DIM + k];
            acc[i][0] += xv * wv.x;
            acc[i][1] += xv * wv.y;
            acc[i][2] += xv * wv.z;
            acc[i][3] += xv * wv.w;
        }
    }
    float4* h4 = (float4*)(hout + r0 * E_DIM);
#pragma unroll
    for (int i = 0; i < 8; ++i) {
        float4 o;
        o.x = acc[i][0]; o.y = acc[i][1]; o.z = acc[i][2]; o.w = acc[i][3];
        h4[(rg * 8 + i) * 32 + cq] = o;
    }
}

// ---------------------------------------------------------------------------
// Kernel 2: chunked decayed scan. Writes f16 LOCAL prefix into sb16 (carry
// applied inside k_main), f16 transposed h into hT[a][pos], fp32 chunk
// carry-out f_j into fc.
// ---------------------------------------------------------------------------
__global__ __launch_bounds__(128) void k_scan(const float* __restrict__ h,
                                              u16* __restrict__ sb16,
                                              float* __restrict__ fc,
                                              u16* __restrict__ hT) {
    const int b = blockIdx.x >> 5;
    const int j = blockIdx.x & 31;
    const int e = threadIdx.x;
    const float inv_d = (float)(1.0 / 1.2);
    const int pos0 = b * S_LEN + j * CHUNK;
    long base = (long)pos0 * E_DIM + e;
    float carry = 0.f;
    union { u16 u[8]; uint4 v; } hb;
#pragma unroll 1
    for (int i0 = 0; i0 < CHUNK; i0 += 8) {
#pragma unroll
        for (int k = 0; k < 8; ++k) {
            float hv = h[base + (long)(i0 + k) * E_DIM];
            union { f16 f; u16 u; } cu; cu.f = (f16)carry;
            sb16[base + (long)(i0 + k) * E_DIM] = cu.u;
            union { f16 f; u16 u; } hu; hu.f = (f16)hv;
            hb.u[k] = hu.u;
            carry = (carry + hv) * inv_d;
        }
        *(uint4*)&hT[(size_t)e * BS + pos0 + i0] = hb.v;
    }
    fc[(b * NCHUNK + j) * E_DIM + e] = carry;
}

// ---------------------------------------------------------------------------
// Kernel 3 (main): f16 MFMA einsum with counted-vmcnt pipeline (T3+T4).
// Grid 256 = (mb 0..63) x (r 0..3).  Block: 512 thr = 8 waves, owns 256 rows
// x 128 c x 32 a-slices (K-split 4).  Wave (rbp=w>>1 in 0..3, ntp=w&1) owns
// 64 rows x 64 c.  W a-slices in a 4-buffer LDS ring, 2-deep prefetch via
// global_load_lds w=16; ONE s_barrier per slice, vmcnt counted (4) so loads
// stay in flight across barriers (vmcnt(0) only for last 2 slices).  No
// in-loop vmem except staging -> exact FIFO counting.  h values pre-staged
// to LDS (read via ds, lgkmcnt).  s packed f16x2 in 64 VGPRs.
// ---------------------------------------------------------------------------
__global__ __launch_bounds__(512, 2) void k_main(const u16* __restrict__ hT,
                                                 const u16* __restrict__ sb16,
                                                 const float* __restrict__ fc,
                                                 const u16* __restrict__ wb,
                                                 float* __restrict__ out,
                                                 float dm64) {
    __shared__ u16 Wl[4][16384];      // 128 KB ring
    __shared__ u16 h16[32 * 256];     // [a_local][row_local], 16 KB
    __shared__ float carr[4][E_DIM];  // 2 KB
    const int t = threadIdx.x;        // 0..511
    const int w = t >> 6, l = t & 63;
    const int l31 = l & 31, hi = l >> 5;
    const int mb = blockIdx.x >> 2, r = blockIdx.x & 3;
    const int rbp = w >> 1;           // 64-row band 0..3
    const int ntp = w & 1;            // 64-col band 0..1
    const int row_base = mb * 256;

    const u16* wbK = wb + (size_t)(r * 32) * 16384;

#define STAGE(buf, sl) {                                                          \
    const u16* gsrc = wbK + (size_t)(sl) * 16384 + t * 8;                         \
    _Pragma("unroll")                                                             \
    for (int i = 0; i < 4; ++i)                                                   \
        __builtin_amdgcn_global_load_lds(                                         \
            (const __attribute__((address_space(1))) void*)(gsrc + i * 4096),     \
            (__attribute__((address_space(3))) void*)&Wl[buf][t * 8 + i * 4096],  \
            16, 0, 0); }

    STAGE(0, 0);
    STAGE(1, 1);

    // fused k_carry: carry into this block's 4 chunks (loads pipeline; only
    // the accumulate is dependent)
    const int bb = row_base >> 11;
    const int j0 = (row_base >> 6) & 31;
    {
        const int ch = t >> 7, e = t & 127;
        float c = 0.f;
        for (int jj = 0; jj < j0 + ch; ++jj)
            c = fc[(bb * NCHUNK + jj) * E_DIM + e] + c * dm64;
        carr[ch][e] = c;
    }
    // h16 stage: hT[r*32+al][row_base + rl] -> h16[al][rl]
    {
        const int al = t >> 4, rl0 = (t & 15) * 16;
        const u16* src = hT + (size_t)(r * 32 + al) * BS + row_base + rl0;
        uint4 v0 = ((const uint4*)src)[0];
        uint4 v1 = ((const uint4*)src)[1];
        *(uint4*)&h16[al * 256 + rl0] = v0;
        *(uint4*)&h16[al * 256 + rl0 + 8] = v1;
    }
    __syncthreads();   // carr + h16 visible (drains prologue vmem incl. L0/L1)

    // fused k_fix: s2 = f16(local_prefix + carry * 1.2^-i)
    const float L2D = 0.26303440583379383f;
    f16x2 s2[2][32];
#pragma unroll
    for (int rb = 0; rb < 2; ++rb) {
        const int row = row_base + rbp * 64 + rb * 32 + l31;
        const float f = exp2f(-L2D * (float)(row & 63));
        const uint4* sp = (const uint4*)(sb16 + (size_t)row * E_DIM + hi * 8);
#pragma unroll
        for (int ks = 0; ks < 8; ++ks) {
            union { uint4 u; u16 us[8]; } uu; uu.u = sp[ks * 2];
            const float* cp = &carr[rbp][ks * 16 + hi * 8];
#pragma unroll
            for (int q = 0; q < 4; ++q) {
                union { f16 f; u16 u; } a0; a0.u = uu.us[2 * q];
                union { f16 f; u16 u; } a1; a1.u = uu.us[2 * q + 1];
                f16x2 pr;
                pr.x = (f16)((float)a0.f + cp[2 * q] * f);
                pr.y = (f16)((float)a1.f + cp[2 * q + 1] * f);
                s2[rb][ks * 4 + q] = pr;
            }
        }
    }

    f32x16 acc[2][2];
#pragma unroll
    for (int rb = 0; rb < 2; ++rb)
#pragma unroll
        for (int nt = 0; nt < 2; ++nt)
#pragma unroll
            for (int g = 0; g < 16; ++g) acc[rb][nt][g] = 0.f;

    const int sxb = l31 & 15;
    const int wcoff = (ntp * 64 + l31) * E_DIM;
    const int hoff0 = rbp * 64 + l31;

#pragma unroll 1
    for (int sl = 0; sl < 32; ++sl) {
        // counted wait: slice sl's 4 loads (oldest) done; sl+1's may fly
        if (sl < 30) { asm volatile("s_waitcnt vmcnt(4)" ::: "memory"); }
        else         { asm volatile("s_waitcnt vmcnt(0)" ::: "memory"); }
        __builtin_amdgcn_s_barrier();
        if (sl < 30) { STAGE((sl + 2) & 3, sl + 2); }

        // h from LDS (lgkmcnt path — keeps vmcnt counting exact)
        u16 hv0 = h16[sl * 256 + hoff0];
        u16 hv1 = h16[sl * 256 + hoff0 + 32];
        union { u16 u[2]; f16x2 v; } hu0, hu1;
        hu0.u[0] = hv0; hu0.u[1] = hv0;
        hu1.u[0] = hv1; hu1.u[1] = hv1;

        const u16* Wc = &Wl[sl & 3][wcoff];
        __builtin_amdgcn_s_setprio(1);
#pragma unroll
        for (int ks = 0; ks < 8; ++ks) {
            const int sx = ((ks << 1) + hi) ^ sxb;
            f16x8 b0 = *(const f16x8*)(Wc + sx * 8);
            f16x8 b1 = *(const f16x8*)(Wc + 32 * E_DIM + sx * 8);
            union { f16x2 h2[4]; f16x8 v; } a0, a1;
#pragma unroll
            for (int q = 0; q < 4; ++q) {
                a0.h2[q] = hu0.v * s2[0][ks * 4 + q];
                a1.h2[q] = hu1.v * s2[1][ks * 4 + q];
            }
            acc[0][0] = __builtin_amdgcn_mfma_f32_32x32x16_f16(a0.v, b0, acc[0][0], 0, 0, 0);
            acc[0][1] = __builtin_amdgcn_mfma_f32_32x32x16_f16(a0.v, b1, acc[0][1], 0, 0, 0);
            acc[1][0] = __builtin_amdgcn_mfma_f32_32x32x16_f16(a1.v, b0, acc[1][0], 0, 0, 0);
            acc[1][1] = __builtin_amdgcn_mfma_f32_32x32x16_f16(a1.v, b1, acc[1][1], 0, 0, 0);
        }
        __builtin_amdgcn_s_setprio(0);
    }
#undef STAGE

    // epilogue: K-split partials via hw fp32 atomics (out pre-zeroed)
#pragma unroll
    for (int rb = 0; rb < 2; ++rb)
#pragma unroll
        for (int nt = 0; nt < 2; ++nt)
#pragma unroll
            for (int g = 0; g < 16; ++g) {
                int rowl = (g & 3) + 8 * (g >> 2) + 4 * hi;   // m101 C/D map
                long row = (long)row_base + rbp * 64 + rb * 32 + rowl;
                int col = ntp * 64 + nt * 32 + l31;
                unsafeAtomicAdd(&out[row * E_DIM + col], acc[rb][nt][g]);
            }
}

// ---------------------------------------------------------------------------
// Kernel 4: residual + LayerNorm, in place on d_out. 8 rows/block.
// ---------------------------------------------------------------------------
__global__ __launch_bounds__(256) void k_ln(float* __restrict__ out,
                                            const float* __restrict__ h,
                                            const float* __restrict__ gamma,
                                            const float* __restrict__ beta) {
    const int t = threadIdx.x;
    const int l32 = t & 31, rl = t >> 5;
    const long row = (long)blockIdx.x * 8 + rl;
    float4 v  = ((const float4*)out)[row * 32 + l32];
    float4 hv = ((const float4*)h)[row * 32 + l32];
    v.x += hv.x; v.y += hv.y; v.z += hv.z; v.w += hv.w;
    float ls = v.x + v.y + v.z + v.w;
    float lq = v.x * v.x + v.y * v.y + v.z * v.z + v.w * v.w;
#pragma unroll
    for (int m = 1; m < 32; m <<= 1) {
        ls += __shfl_xor(ls, m, 64);
        lq += __shfl_xor(lq, m, 64);
    }
    float mean = ls * (1.f / 128.f);
    float var  = lq * (1.f / 128.f) - mean * mean;
    float inv  = rsqrtf(var + 1e-3f);
    float4 g = ((const float4*)gamma)[l32];
    float4 b = ((const float4*)beta)[l32];
    float4 o;
    o.x = (v.x - mean) * inv * g.x + b.x;
    o.y = (v.y - mean) * inv * g.y + b.y;
    o.z = (v.z - mean) * inv * g.z + b.z;
    o.w = (v.w - mean) * inv * g.w + b.w;
    ((float4*)out)[row * 32 + l32] = o;
}

// ---------------------------------------------------------------------------
extern "C" void kernel_launch(void* const* d_in, const int* in_sizes, int n_in,
                              void* d_out, int out_size, void* d_ws, size_t ws_size,
                              hipStream_t stream) {
    const float* x     = (const float*)d_in[0];
    const float* dw    = (const float*)d_in[1];
    const float* db    = (const float*)d_in[2];
    const float* cm    = (const float*)d_in[3];
    const float* gamma = (const float*)d_in[4];
    const float* beta  = (const float*)d_in[5];
    float* outp = (float*)d_out;

    float* ws = (float*)d_ws;
    float* h    = ws;                                     // BS*E f32 (8 MB)
    float* fc   = ws + (size_t)BS * E_DIM;                // 32768 f32 (raw f_j)
    u16*   wb   = (u16*)(fc + B_N * NCHUNK * E_DIM);      // E^3 f16 (4 MB)
    u16*   hT   = wb + (size_t)2097152;                   // [a][pos] f16 (4 MB)
    u16*   sb16 = hT + (size_t)BS * E_DIM;                // [pos][p] f16 (4 MB)

    float dm64 = (float)pow(1.2, -64.0);   // host-side, pure CPU

    hipMemsetAsync(d_out, 0, (size_t)BS * E_DIM * sizeof(float), stream);
    k_pre <<<dim3(1280), dim3(256), 0, stream>>>(x, dw, db, cm, h, wb);
    k_scan<<<dim3(B_N * NCHUNK), dim3(128), 0, stream>>>(h, sb16, fc, hT);
    k_main<<<dim3(256), dim3(512), 0, stream>>>(hT, sb16, fc, wb, outp, dm64);
    k_ln  <<<dim3(BS / 8), dim3(256), 0, stream>>>(outp, h, gamma, beta);
}